// Round 1
// baseline (199.835 us; speedup 1.0000x reference)
//
#include <hip/hip_runtime.h>
#include <hip/hip_bf16.h>

#define B_ 8
#define C_ 512
#define N_ 1024
#define HEADS_ 4
#define DK_ 128
#define R_ 128

typedef float f32x4 __attribute__((ext_vector_type(4)));
typedef __bf16 bf16x8 __attribute__((ext_vector_type(8)));
typedef unsigned short u16;

constexpr float kScale = 0.08838834764831845f; // 1/sqrt(128)

// ---- workspace layout (bytes) ----
#define OFF_P   0u                       // p[B][C] f32            16KB
#define OFF_SS  16384u                   // 1+sigmoid(f) [B][C]    16KB
#define OFF_WB  32768u                   // wq/wk/wv bf16 [3][C][C] 1.5MB
#define OFF_XT  1605632u                 // x1^T [B][N][C] bf16    8MB
#define OFF_QT  9994240u                 // q^T  [B][N][C] bf16    8MB
#define OFF_KT  18382848u                // k^T  [B][N][C] bf16    8MB
#define OFF_V   26771456u                // v    [B][C][N] bf16    8MB
#define OFF_DEN 35160064u                // invden [B*H][N] f32    128KB

__device__ __forceinline__ u16 f2b(float f) {
  __hip_bfloat16 h = __float2bfloat16(f);
  return __builtin_bit_cast(u16, h);
}

typedef const __attribute__((address_space(1))) unsigned int* gptr_t;
typedef __attribute__((address_space(3))) unsigned int* lptr_t;
__device__ __forceinline__ void gload16(const void* g, void* l) {
  __builtin_amdgcn_global_load_lds((gptr_t)g, (lptr_t)l, 16, 0, 0);
}

__device__ __forceinline__ f32x4 mfma16(bf16x8 a, bf16x8 b, f32x4 c) {
  return __builtin_amdgcn_mfma_f32_16x16x32_bf16(a, b, c, 0, 0, 0);
}

// ---------------- pool: p[b][c] = mean_n x[b][c][n] ----------------
__global__ __launch_bounds__(64) void k_pool(const float* __restrict__ x,
                                             float* __restrict__ p) {
  int bc = blockIdx.x, lane = threadIdx.x;
  const float4* row = (const float4*)(x + (size_t)bc * N_);
  float s = 0.f;
  for (int i = lane; i < N_ / 4; i += 64) {
    float4 t = row[i];
    s += t.x + t.y + t.z + t.w;
  }
  for (int o = 32; o > 0; o >>= 1) s += __shfl_down(s, o, 64);
  if (lane == 0) p[bc] = s * (1.0f / N_);
}

// ---------------- SE MLP: sscale = 1 + sigmoid(fc2(relu(fc1(p)))) ----------------
__global__ __launch_bounds__(256) void k_se(const float* __restrict__ p,
                                            const float* __restrict__ fc1w,
                                            const float* __restrict__ fc1b,
                                            const float* __restrict__ fc2w,
                                            const float* __restrict__ fc2b,
                                            float* __restrict__ ss) {
  __shared__ float pl[C_];
  __shared__ float f1[R_];
  int b = blockIdx.x, t = threadIdx.x;
  for (int c = t; c < C_; c += 256) pl[c] = p[b * C_ + c];
  __syncthreads();
  if (t < R_) {
    float a = fc1b[t];
    for (int c = 0; c < C_; c++) a += pl[c] * fc1w[t * C_ + c];
    f1[t] = fmaxf(a, 0.f);
  }
  __syncthreads();
  for (int c = t; c < C_; c += 256) {
    float a = fc2b[c];
    for (int j = 0; j < R_; j++) a += f1[j] * fc2w[c * R_ + j];
    ss[b * C_ + c] = 1.f + 1.f / (1.f + __expf(-a));
  }
}

// ---------------- cast weights to bf16 ----------------
__global__ __launch_bounds__(256) void k_castw(const float* __restrict__ wq,
                                               const float* __restrict__ wk,
                                               const float* __restrict__ wv,
                                               u16* __restrict__ wb) {
  int i = blockIdx.x * 256 + threadIdx.x;
  int idx = i * 4;
  const float* srcs[3] = {wq, wk, wv};
  int w = idx / (C_ * C_), off = idx % (C_ * C_);
  float4 v = *(const float4*)(srcs[w] + off);
  u16* d = wb + idx;
  d[0] = f2b(v.x); d[1] = f2b(v.y); d[2] = f2b(v.z); d[3] = f2b(v.w);
}

// ---------------- x1^T[b][n][c] = bf16(x[b][c][n] * ss[b][c]) ----------------
__global__ __launch_bounds__(256) void k_xt(const float* __restrict__ x,
                                            const float* __restrict__ ss,
                                            u16* __restrict__ xt) {
  int b = blockIdx.z, c0 = blockIdx.y * 64, n0 = blockIdx.x * 64;
  __shared__ float tile[64][65];
  int t = threadIdx.x;
  int cr = t >> 4, nc4 = (t & 15) * 4;
  for (int j = 0; j < 4; j++) {
    int c = cr + j * 16;
    float sc = ss[b * C_ + c0 + c];
    float4 v = *(const float4*)(x + ((size_t)b * C_ + c0 + c) * N_ + n0 + nc4);
    tile[c][nc4 + 0] = v.x * sc;
    tile[c][nc4 + 1] = v.y * sc;
    tile[c][nc4 + 2] = v.z * sc;
    tile[c][nc4 + 3] = v.w * sc;
  }
  __syncthreads();
  int nr = t >> 2, cc = (t & 3) * 16;
  u16 ov[16];
  for (int m = 0; m < 16; m++) ov[m] = f2b(tile[cc + m][nr]);
  u16* dst = xt + ((size_t)b * N_ + n0 + nr) * C_ + c0 + cc;
  for (int m = 0; m < 16; m++) dst[m] = ov[m];
}

// ---------------- QKV GEMM (bf16 MFMA, 128x128 tile, BK=64) ----------------
// sel 0/1: q^T/k^T[n][o] = sum_c x1t[n][c] * w[o][c]   (A=x1t, B=w)
// sel 2  : v[o][n]       = sum_c w[o][c]  * x1t[n][c]  (A=w,  B=x1t)
__global__ __launch_bounds__(256) void k_qkv(const u16* __restrict__ xt,
                                             const u16* __restrict__ wb,
                                             const float* __restrict__ bq,
                                             const float* __restrict__ bk,
                                             const float* __restrict__ bv,
                                             u16* __restrict__ qt,
                                             u16* __restrict__ kt,
                                             u16* __restrict__ v) {
  __shared__ char smem[32768]; // A tile 16KB | B tile 16KB, reused as 32KB out-stage
  int b = blockIdx.y / 3, sel = blockIdx.y % 3;
  int tile = blockIdx.x;
  const char *Ab, *Bb;
  u16* out;
  const float* bias;
  int mt, nt, rstride;
  size_t xtoff = (size_t)b * N_ * C_;
  if (sel < 2) {
    mt = tile & 7; nt = tile >> 3;
    Ab = (const char*)(xt + xtoff + (size_t)mt * 128 * C_);
    Bb = (const char*)(wb + (size_t)sel * C_ * C_ + (size_t)nt * 128 * C_);
    out = (sel ? kt : qt) + xtoff;
    bias = sel ? bk : bq;
    rstride = C_ * 2;
  } else {
    mt = tile & 3; nt = tile >> 2;
    Ab = (const char*)(wb + (size_t)2 * C_ * C_ + (size_t)mt * 128 * C_);
    Bb = (const char*)(xt + xtoff + (size_t)nt * 128 * C_);
    out = v + (size_t)b * C_ * N_;
    bias = bv;
    rstride = N_ * 2;
  }
  int t = threadIdx.x, lane = t & 63, wid = t >> 6;
  int wr = wid >> 1, wc = wid & 1;
  const f32x4 z4 = {0.f, 0.f, 0.f, 0.f};
  f32x4 acc[4][4];
  for (int i = 0; i < 4; i++)
    for (int j = 0; j < 4; j++) acc[i][j] = z4;

  char* lA = smem;
  char* lB = smem + 16384;
  for (int ko = 0; ko < C_; ko += 64) {
    __syncthreads();
    for (int i = wid; i < 16; i += 4) {
      int beta = i * 1024 + lane * 16;
      int row = beta >> 7, cb = (beta & 127) ^ ((row & 7) << 4);
      gload16(Ab + (size_t)row * 1024 + ko * 2 + cb, lA + beta);
    }
    for (int i = wid; i < 16; i += 4) {
      int beta = i * 1024 + lane * 16;
      int row = beta >> 7, cb = (beta & 127) ^ ((row & 7) << 4);
      gload16(Bb + (size_t)row * 1024 + ko * 2 + cb, lB + beta);
    }
    __syncthreads();
    for (int ks = 0; ks < 2; ks++) {
      int kb = ks * 64 + (lane >> 4) * 16;
      bf16x8 af[4], bfr[4];
      for (int fi = 0; fi < 4; fi++) {
        int row = wr * 64 + fi * 16 + (lane & 15);
        af[fi] = *(const bf16x8*)(lA + row * 128 + (kb ^ ((row & 7) << 4)));
      }
      for (int fj = 0; fj < 4; fj++) {
        int row = wc * 64 + fj * 16 + (lane & 15);
        bfr[fj] = *(const bf16x8*)(lB + row * 128 + (kb ^ ((row & 7) << 4)));
      }
      for (int fi = 0; fi < 4; fi++)
        for (int fj = 0; fj < 4; fj++)
          acc[fi][fj] = mfma16(af[fi], bfr[fj], acc[fi][fj]);
    }
  }
  // epilogue: bias + bf16 + LDS restage for coalesced stores
  __syncthreads();
  for (int fi = 0; fi < 4; fi++)
    for (int fj = 0; fj < 4; fj++) {
      int colb = wc * 64 + fj * 16 + (lane & 15);
      for (int r = 0; r < 4; r++) {
        int rowb = wr * 64 + fi * 16 + (lane >> 4) * 4 + r;
        float bva = (sel < 2) ? bias[nt * 128 + colb] : bias[mt * 128 + rowb];
        float val = acc[fi][fj][r] + bva;
        int byte = rowb * 256 + ((colb * 2) ^ ((rowb & 7) << 4));
        *(u16*)(smem + byte) = f2b(val);
      }
    }
  __syncthreads();
  for (int i = t; i < 2048; i += 256) {
    int row = i >> 4, cb = (i & 15) * 16;
    bf16x8 val = *(const bf16x8*)(smem + row * 256 + (cb ^ ((row & 7) << 4)));
    *(bf16x8*)((char*)out + (size_t)(mt * 128 + row) * rstride + nt * 256 + cb) = val;
  }
}

// ---------------- pass A: invden[bh][n] = 1/sum_m exp(scale*S[n,m]) ----------------
__global__ __launch_bounds__(256) void k_passA(const u16* __restrict__ qt,
                                               const u16* __restrict__ kt,
                                               float* __restrict__ invden) {
  __shared__ char lK[32768]; // [128 m][128 d] swizzled
  int nb = blockIdx.x * 64, bh = blockIdx.y;
  int b = bh >> 2, h = bh & 3;
  const char* qb = (const char*)(qt + (size_t)b * N_ * C_ + h * DK_);
  const char* kb = (const char*)(kt + (size_t)b * N_ * C_ + h * DK_);
  int t = threadIdx.x, lane = t & 63, wid = t >> 6;
  bf16x8 aq[4];
  {
    const char* qr = qb + (size_t)(nb + wid * 16 + (lane & 15)) * (C_ * 2);
    for (int ks = 0; ks < 4; ks++)
      aq[ks] = *(const bf16x8*)(qr + ks * 64 + (lane >> 4) * 16);
  }
  float sacc[4] = {0.f, 0.f, 0.f, 0.f};
  const f32x4 z4 = {0.f, 0.f, 0.f, 0.f};
  for (int mc = 0; mc < 8; mc++) {
    __syncthreads();
    for (int i = wid; i < 32; i += 4) {
      int beta = i * 1024 + lane * 16;
      int row = beta >> 8, cb = (beta & 255) ^ ((row & 7) << 4);
      gload16(kb + (size_t)(mc * 128 + row) * (C_ * 2) + cb, lK + beta);
    }
    __syncthreads();
    for (int fj = 0; fj < 8; fj++) {
      f32x4 s = z4;
      for (int ks = 0; ks < 4; ks++) {
        int row = fj * 16 + (lane & 15);
        bf16x8 bk_ = *(const bf16x8*)(lK + row * 256 +
                                      ((ks * 64 + (lane >> 4) * 16) ^ ((row & 7) << 4)));
        s = mfma16(aq[ks], bk_, s);
      }
      for (int r = 0; r < 4; r++) sacc[r] += __expf(s[r] * kScale);
    }
  }
  for (int r = 0; r < 4; r++) {
    float vv = sacc[r];
    for (int m = 1; m < 16; m <<= 1) vv += __shfl_xor(vv, m, 64);
    sacc[r] = vv;
  }
  if ((lane & 15) == 0) {
    int n = nb + wid * 16 + (lane >> 4) * 4;
    for (int r = 0; r < 4; r++) invden[(size_t)bh * N_ + n + r] = 1.f / sacc[r];
  }
}

// ---------------- pass B: o[d][mb+m] = sum_n v[d,n] * exp(scale*S[n,m])*invden[n] ----------------
__global__ __launch_bounds__(256) void k_passB(const u16* __restrict__ qt,
                                               const u16* __restrict__ kt,
                                               const u16* __restrict__ v,
                                               const float* __restrict__ invden,
                                               float* __restrict__ out) {
  __shared__ char lQ[16384]; // [64 n][128 d]
  __shared__ char lV[16384]; // [128 d][64 n]
  __shared__ char lP[8192];  // [64 m][64 n] bf16
  int mb = blockIdx.x * 64, bh = blockIdx.y;
  int b = bh >> 2, h = bh & 3;
  const char* qb = (const char*)(qt + (size_t)b * N_ * C_ + h * DK_);
  const char* kb = (const char*)(kt + (size_t)b * N_ * C_ + h * DK_);
  const char* vb = (const char*)(v + ((size_t)b * C_ + h * DK_) * N_);
  float* ob = out + ((size_t)b * C_ + h * DK_) * N_ + mb;
  int t = threadIdx.x, lane = t & 63, wid = t >> 6;
  bf16x8 ak[4];
  {
    const char* kr = kb + (size_t)(mb + wid * 16 + (lane & 15)) * (C_ * 2);
    for (int ks = 0; ks < 4; ks++)
      ak[ks] = *(const bf16x8*)(kr + ks * 64 + (lane >> 4) * 16);
  }
  const f32x4 z4 = {0.f, 0.f, 0.f, 0.f};
  f32x4 oacc[2][4];
  for (int i = 0; i < 2; i++)
    for (int j = 0; j < 4; j++) oacc[i][j] = z4;

  for (int nc = 0; nc < 16; nc++) {
    int n0 = nc * 64;
    __syncthreads();
    for (int i = wid; i < 16; i += 4) {
      int beta = i * 1024 + lane * 16;
      int row = beta >> 8, cb = (beta & 255) ^ ((row & 7) << 4);
      gload16(qb + (size_t)(n0 + row) * (C_ * 2) + cb, lQ + beta);
    }
    for (int i = wid; i < 16; i += 4) {
      int beta = i * 1024 + lane * 16;
      int row = beta >> 7, cb = (beta & 127) ^ ((row & 7) << 4);
      gload16(vb + (size_t)row * (N_ * 2) + n0 * 2 + cb, lV + beta);
    }
    __syncthreads();
    // S^T tile [64m][64n] + P = exp(scale*S)*invden[n] -> lP (bf16)
    for (int fj = 0; fj < 4; fj++) {
      f32x4 s = z4;
      for (int ks = 0; ks < 4; ks++) {
        int row = fj * 16 + (lane & 15);
        bf16x8 bq_ = *(const bf16x8*)(lQ + row * 256 +
                                      ((ks * 64 + (lane >> 4) * 16) ^ ((row & 7) << 4)));
        s = mfma16(ak[ks], bq_, s);
      }
      float iden = invden[(size_t)bh * N_ + n0 + fj * 16 + (lane & 15)];
      for (int r = 0; r < 4; r++) {
        float pval = __expf(s[r] * kScale) * iden;
        int ml = wid * 16 + (lane >> 4) * 4 + r;
        int nl2 = (fj * 16 + (lane & 15)) * 2;
        *(u16*)(lP + ml * 128 + (nl2 ^ ((ml & 7) << 4))) = f2b(pval);
      }
    }
    __syncthreads();
    // PV: wave owns d rows [32w,32w+32), all 64 m cols
    for (int ks = 0; ks < 2; ks++) {
      int kb2 = ks * 64 + (lane >> 4) * 16;
      bf16x8 av[2], bp[4];
      for (int fi = 0; fi < 2; fi++) {
        int row = wid * 32 + fi * 16 + (lane & 15);
        av[fi] = *(const bf16x8*)(lV + row * 128 + (kb2 ^ ((row & 7) << 4)));
      }
      for (int fm = 0; fm < 4; fm++) {
        int row = fm * 16 + (lane & 15);
        bp[fm] = *(const bf16x8*)(lP + row * 128 + (kb2 ^ ((row & 7) << 4)));
      }
      for (int fi = 0; fi < 2; fi++)
        for (int fm = 0; fm < 4; fm++)
          oacc[fi][fm] = mfma16(av[fi], bp[fm], oacc[fi][fm]);
    }
  }
  for (int fi = 0; fi < 2; fi++)
    for (int fm = 0; fm < 4; fm++)
      for (int r = 0; r < 4; r++) {
        int d = wid * 32 + fi * 16 + (lane >> 4) * 4 + r;
        int m = fm * 16 + (lane & 15);
        ob[(size_t)d * N_ + m] = oacc[fi][fm][r];
      }
}

// ---------------- gate: out = o * (1 + sigmoid(gw.o + gb)), in place ----------------
__global__ __launch_bounds__(256) void k_gate(const float* __restrict__ gw,
                                              const float* __restrict__ gb,
                                              float* __restrict__ out) {
  __shared__ float part[2][128];
  __shared__ float gl[128];
  int b = blockIdx.y, m0 = blockIdx.x * 128;
  float* ob = out + (size_t)b * C_ * N_ + m0;
  int t = threadIdx.x, cp = t >> 7, m = t & 127;
  float a = 0.f;
  for (int c = cp; c < C_; c += 2) a += gw[c] * ob[(size_t)c * N_ + m];
  part[cp][m] = a;
  __syncthreads();
  if (t < 128) {
    float g = part[0][t] + part[1][t] + gb[0];
    gl[t] = 1.f + 1.f / (1.f + __expf(-g));
  }
  __syncthreads();
  for (int i = t; i < C_ * 128; i += 256) {
    int c = i >> 7, mm = i & 127;
    ob[(size_t)c * N_ + mm] *= gl[mm];
  }
}

extern "C" void kernel_launch(void* const* d_in, const int* in_sizes, int n_in,
                              void* d_out, int out_size, void* d_ws, size_t ws_size,
                              hipStream_t stream) {
  const float* x    = (const float*)d_in[0];
  const float* wq   = (const float*)d_in[1];
  const float* bq   = (const float*)d_in[2];
  const float* wk   = (const float*)d_in[3];
  const float* bk   = (const float*)d_in[4];
  const float* wv   = (const float*)d_in[5];
  const float* bv   = (const float*)d_in[6];
  const float* fc1w = (const float*)d_in[7];
  const float* fc1b = (const float*)d_in[8];
  const float* fc2w = (const float*)d_in[9];
  const float* fc2b = (const float*)d_in[10];
  const float* gw   = (const float*)d_in[11];
  const float* gb   = (const float*)d_in[12];
  float* out = (float*)d_out;
  char* ws = (char*)d_ws;

  float* p   = (float*)(ws + OFF_P);
  float* ssc = (float*)(ws + OFF_SS);
  u16* wb  = (u16*)(ws + OFF_WB);
  u16* xt  = (u16*)(ws + OFF_XT);
  u16* qt  = (u16*)(ws + OFF_QT);
  u16* kt  = (u16*)(ws + OFF_KT);
  u16* v   = (u16*)(ws + OFF_V);
  float* den = (float*)(ws + OFF_DEN);

  k_pool<<<B_ * C_, 64, 0, stream>>>(x, p);
  k_castw<<<768, 256, 0, stream>>>(wq, wk, wv, wb);
  k_se<<<B_, 256, 0, stream>>>(p, fc1w, fc1b, fc2w, fc2b, ssc);
  k_xt<<<dim3(16, 8, B_), 256, 0, stream>>>(x, ssc, xt);
  k_qkv<<<dim3(32, B_ * 3), 256, 0, stream>>>(xt, wb, bq, bk, bv, qt, kt, v);
  k_passA<<<dim3(16, 32), 256, 0, stream>>>(qt, kt, den);
  k_passB<<<dim3(16, 32), 256, 0, stream>>>(qt, kt, v, den, out);
  k_gate<<<dim3(8, B_), 256, 0, stream>>>(gw, gb, out);
}

// Round 2
// 150.901 us; speedup vs baseline: 1.3243x; 1.3243x over previous
//
#include <hip/hip_runtime.h>
#include <hip/hip_bf16.h>

#define B_ 8
#define C_ 512
#define N_ 1024
#define HEADS_ 4
#define DK_ 128
#define R_ 128

typedef float f32x4 __attribute__((ext_vector_type(4)));
typedef __bf16 bf16x8 __attribute__((ext_vector_type(8)));
typedef unsigned short u16;

constexpr float kScale = 0.08838834764831845f; // 1/sqrt(128)

// ---- workspace layout (bytes) ----
#define OFF_P   0u                       // p[B][C] f32            16KB
#define OFF_SS  16384u                   // 1+sigmoid(f) [B][C]    16KB
#define OFF_WB  32768u                   // wq/wk/wv bf16 [3][C][C] 1.5MB
#define OFF_XT  1605632u                 // x1^T [B][N][C] bf16    8MB
#define OFF_QT  9994240u                 // q^T  [B][N][C] bf16    8MB
#define OFF_KT  18382848u                // k^T  [B][N][C] bf16    8MB
#define OFF_V   26771456u                // v    [B][C][N] bf16    8MB
#define OFF_DEN 35160064u                // invden [B*H][N] f32    128KB
#define OFF_G   35291136u                // gate dot [B][N] f32    32KB

__device__ __forceinline__ u16 f2b(float f) {
  __hip_bfloat16 h = __float2bfloat16(f);
  return __builtin_bit_cast(u16, h);
}

typedef const __attribute__((address_space(1))) unsigned int* gptr_t;
typedef __attribute__((address_space(3))) unsigned int* lptr_t;
__device__ __forceinline__ void gload16(const void* g, void* l) {
  __builtin_amdgcn_global_load_lds((gptr_t)g, (lptr_t)l, 16, 0, 0);
}

__device__ __forceinline__ f32x4 mfma16(bf16x8 a, bf16x8 b, f32x4 c) {
  return __builtin_amdgcn_mfma_f32_16x16x32_bf16(a, b, c, 0, 0, 0);
}

// ---------------- pool: p[b][c] = mean_n x[b][c][n] ----------------
__global__ __launch_bounds__(64) void k_pool(const float* __restrict__ x,
                                             float* __restrict__ p) {
  int bc = blockIdx.x, lane = threadIdx.x;
  const float4* row = (const float4*)(x + (size_t)bc * N_);
  float s = 0.f;
  for (int i = lane; i < N_ / 4; i += 64) {
    float4 t = row[i];
    s += t.x + t.y + t.z + t.w;
  }
  for (int o = 32; o > 0; o >>= 1) s += __shfl_down(s, o, 64);
  if (lane == 0) p[bc] = s * (1.0f / N_);
}

// ---------------- SE MLP: sscale = 1 + sigmoid(fc2(relu(fc1(p)))) ----------------
__global__ __launch_bounds__(256) void k_se(const float* __restrict__ p,
                                            const float* __restrict__ fc1w,
                                            const float* __restrict__ fc1b,
                                            const float* __restrict__ fc2w,
                                            const float* __restrict__ fc2b,
                                            float* __restrict__ ss) {
  __shared__ float pl[C_];
  __shared__ float f1[R_];
  int b = blockIdx.x, t = threadIdx.x;
  for (int c = t; c < C_; c += 256) pl[c] = p[b * C_ + c];
  __syncthreads();
  if (t < R_) {
    float a = fc1b[t];
    for (int c = 0; c < C_; c++) a += pl[c] * fc1w[t * C_ + c];
    f1[t] = fmaxf(a, 0.f);
  }
  __syncthreads();
  for (int c = t; c < C_; c += 256) {
    float a = fc2b[c];
    for (int j = 0; j < R_; j++) a += f1[j] * fc2w[c * R_ + j];
    ss[b * C_ + c] = 1.f + 1.f / (1.f + __expf(-a));
  }
}

// ---------------- cast weights to bf16 ----------------
__global__ __launch_bounds__(256) void k_castw(const float* __restrict__ wq,
                                               const float* __restrict__ wk,
                                               const float* __restrict__ wv,
                                               u16* __restrict__ wb) {
  int i = blockIdx.x * 256 + threadIdx.x;
  int idx = i * 4;
  const float* srcs[3] = {wq, wk, wv};
  int w = idx / (C_ * C_), off = idx % (C_ * C_);
  float4 v = *(const float4*)(srcs[w] + off);
  u16* d = wb + idx;
  d[0] = f2b(v.x); d[1] = f2b(v.y); d[2] = f2b(v.z); d[3] = f2b(v.w);
}

// ---------------- x1^T[b][n][c] = bf16(x[b][c][n] * ss[b][c]) ----------------
__global__ __launch_bounds__(256) void k_xt(const float* __restrict__ x,
                                            const float* __restrict__ ss,
                                            u16* __restrict__ xt) {
  int b = blockIdx.z, c0 = blockIdx.y * 64, n0 = blockIdx.x * 64;
  __shared__ float tile[64][65];
  int t = threadIdx.x;
  int cr = t >> 4, nc4 = (t & 15) * 4;
  for (int j = 0; j < 4; j++) {
    int c = cr + j * 16;
    float sc = ss[b * C_ + c0 + c];
    float4 v = *(const float4*)(x + ((size_t)b * C_ + c0 + c) * N_ + n0 + nc4);
    tile[c][nc4 + 0] = v.x * sc;
    tile[c][nc4 + 1] = v.y * sc;
    tile[c][nc4 + 2] = v.z * sc;
    tile[c][nc4 + 3] = v.w * sc;
  }
  __syncthreads();
  int nr = t >> 2, cc = (t & 3) * 16;
  u16 ov[16];
  for (int m = 0; m < 16; m++) ov[m] = f2b(tile[cc + m][nr]);
  u16* dst = xt + ((size_t)b * N_ + n0 + nr) * C_ + c0 + cc;
  for (int m = 0; m < 16; m++) dst[m] = ov[m];
}

// ---------------- QKV GEMM (bf16 MFMA, 128x128 tile, BK=64) ----------------
__global__ __launch_bounds__(256) void k_qkv(const u16* __restrict__ xt,
                                             const u16* __restrict__ wb,
                                             const float* __restrict__ bq,
                                             const float* __restrict__ bk,
                                             const float* __restrict__ bv,
                                             u16* __restrict__ qt,
                                             u16* __restrict__ kt,
                                             u16* __restrict__ v) {
  __shared__ char smem[32768];
  int b = blockIdx.y / 3, sel = blockIdx.y % 3;
  int tile = blockIdx.x;
  const char *Ab, *Bb;
  u16* out;
  const float* bias;
  int mt, nt, rstride;
  size_t xtoff = (size_t)b * N_ * C_;
  if (sel < 2) {
    mt = tile & 7; nt = tile >> 3;
    Ab = (const char*)(xt + xtoff + (size_t)mt * 128 * C_);
    Bb = (const char*)(wb + (size_t)sel * C_ * C_ + (size_t)nt * 128 * C_);
    out = (sel ? kt : qt) + xtoff;
    bias = sel ? bk : bq;
    rstride = C_ * 2;
  } else {
    mt = tile & 3; nt = tile >> 2;
    Ab = (const char*)(wb + (size_t)2 * C_ * C_ + (size_t)mt * 128 * C_);
    Bb = (const char*)(xt + xtoff + (size_t)nt * 128 * C_);
    out = v + (size_t)b * C_ * N_;
    bias = bv;
    rstride = N_ * 2;
  }
  int t = threadIdx.x, lane = t & 63, wid = t >> 6;
  int wr = wid >> 1, wc = wid & 1;
  const f32x4 z4 = {0.f, 0.f, 0.f, 0.f};
  f32x4 acc[4][4];
  for (int i = 0; i < 4; i++)
    for (int j = 0; j < 4; j++) acc[i][j] = z4;

  char* lA = smem;
  char* lB = smem + 16384;
  for (int ko = 0; ko < C_; ko += 64) {
    __syncthreads();
    for (int i = wid; i < 16; i += 4) {
      int beta = i * 1024 + lane * 16;
      int row = beta >> 7, cb = (beta & 127) ^ ((row & 7) << 4);
      gload16(Ab + (size_t)row * 1024 + ko * 2 + cb, lA + beta);
    }
    for (int i = wid; i < 16; i += 4) {
      int beta = i * 1024 + lane * 16;
      int row = beta >> 7, cb = (beta & 127) ^ ((row & 7) << 4);
      gload16(Bb + (size_t)row * 1024 + ko * 2 + cb, lB + beta);
    }
    __syncthreads();
    for (int ks = 0; ks < 2; ks++) {
      int kb = ks * 64 + (lane >> 4) * 16;
      bf16x8 af[4], bfr[4];
      for (int fi = 0; fi < 4; fi++) {
        int row = wr * 64 + fi * 16 + (lane & 15);
        af[fi] = *(const bf16x8*)(lA + row * 128 + (kb ^ ((row & 7) << 4)));
      }
      for (int fj = 0; fj < 4; fj++) {
        int row = wc * 64 + fj * 16 + (lane & 15);
        bfr[fj] = *(const bf16x8*)(lB + row * 128 + (kb ^ ((row & 7) << 4)));
      }
      for (int fi = 0; fi < 4; fi++)
        for (int fj = 0; fj < 4; fj++)
          acc[fi][fj] = mfma16(af[fi], bfr[fj], acc[fi][fj]);
    }
  }
  __syncthreads();
  for (int fi = 0; fi < 4; fi++)
    for (int fj = 0; fj < 4; fj++) {
      int colb = wc * 64 + fj * 16 + (lane & 15);
      for (int r = 0; r < 4; r++) {
        int rowb = wr * 64 + fi * 16 + (lane >> 4) * 4 + r;
        float bva = (sel < 2) ? bias[nt * 128 + colb] : bias[mt * 128 + rowb];
        float val = acc[fi][fj][r] + bva;
        int byte = rowb * 256 + ((colb * 2) ^ ((rowb & 7) << 4));
        *(u16*)(smem + byte) = f2b(val);
      }
    }
  __syncthreads();
  for (int i = t; i < 2048; i += 256) {
    int row = i >> 4, cb = (i & 15) * 16;
    bf16x8 val = *(const bf16x8*)(smem + row * 256 + (cb ^ ((row & 7) << 4)));
    *(bf16x8*)((char*)out + (size_t)(mt * 128 + row) * rstride + nt * 256 + cb) = val;
  }
}

// ---------------- pass A: invden[bh][n] = 1/sum_m exp(scale*S[n,m]) ----------------
__global__ __launch_bounds__(256) void k_passA(const u16* __restrict__ qt,
                                               const u16* __restrict__ kt,
                                               float* __restrict__ invden) {
  __shared__ char lK[32768];
  int nb = blockIdx.x * 64, bh = blockIdx.y;
  int b = bh >> 2, h = bh & 3;
  const char* qb = (const char*)(qt + (size_t)b * N_ * C_ + h * DK_);
  const char* kb = (const char*)(kt + (size_t)b * N_ * C_ + h * DK_);
  int t = threadIdx.x, lane = t & 63, wid = t >> 6;
  bf16x8 aq[4];
  {
    const char* qr = qb + (size_t)(nb + wid * 16 + (lane & 15)) * (C_ * 2);
    for (int ks = 0; ks < 4; ks++)
      aq[ks] = *(const bf16x8*)(qr + ks * 64 + (lane >> 4) * 16);
  }
  float sacc[4] = {0.f, 0.f, 0.f, 0.f};
  const f32x4 z4 = {0.f, 0.f, 0.f, 0.f};
  for (int mc = 0; mc < 8; mc++) {
    __syncthreads();
    for (int i = wid; i < 32; i += 4) {
      int beta = i * 1024 + lane * 16;
      int row = beta >> 8, cb = (beta & 255) ^ ((row & 7) << 4);
      gload16(kb + (size_t)(mc * 128 + row) * (C_ * 2) + cb, lK + beta);
    }
    __syncthreads();
    for (int fj = 0; fj < 8; fj++) {
      f32x4 s = z4;
      for (int ks = 0; ks < 4; ks++) {
        int row = fj * 16 + (lane & 15);
        bf16x8 bk_ = *(const bf16x8*)(lK + row * 256 +
                                      ((ks * 64 + (lane >> 4) * 16) ^ ((row & 7) << 4)));
        s = mfma16(aq[ks], bk_, s);
      }
      for (int r = 0; r < 4; r++) sacc[r] += __expf(s[r] * kScale);
    }
  }
  for (int r = 0; r < 4; r++) {
    float vv = sacc[r];
    for (int m = 1; m < 16; m <<= 1) vv += __shfl_xor(vv, m, 64);
    sacc[r] = vv;
  }
  if ((lane & 15) == 0) {
    int n = nb + wid * 16 + (lane >> 4) * 4;
    for (int r = 0; r < 4; r++) invden[(size_t)bh * N_ + n + r] = 1.f / sacc[r];
  }
}

// ---------------- pass B ----------------
__global__ __launch_bounds__(256) void k_passB(const u16* __restrict__ qt,
                                               const u16* __restrict__ kt,
                                               const u16* __restrict__ v,
                                               const float* __restrict__ invden,
                                               float* __restrict__ out) {
  __shared__ char lQ[16384];
  __shared__ char lV[16384];
  __shared__ char lP[8192];
  int mb = blockIdx.x * 64, bh = blockIdx.y;
  int b = bh >> 2, h = bh & 3;
  const char* qb = (const char*)(qt + (size_t)b * N_ * C_ + h * DK_);
  const char* kb = (const char*)(kt + (size_t)b * N_ * C_ + h * DK_);
  const char* vb = (const char*)(v + ((size_t)b * C_ + h * DK_) * N_);
  float* ob = out + ((size_t)b * C_ + h * DK_) * N_ + mb;
  int t = threadIdx.x, lane = t & 63, wid = t >> 6;
  bf16x8 ak[4];
  {
    const char* kr = kb + (size_t)(mb + wid * 16 + (lane & 15)) * (C_ * 2);
    for (int ks = 0; ks < 4; ks++)
      ak[ks] = *(const bf16x8*)(kr + ks * 64 + (lane >> 4) * 16);
  }
  const f32x4 z4 = {0.f, 0.f, 0.f, 0.f};
  f32x4 oacc[2][4];
  for (int i = 0; i < 2; i++)
    for (int j = 0; j < 4; j++) oacc[i][j] = z4;

  for (int nc = 0; nc < 16; nc++) {
    int n0 = nc * 64;
    __syncthreads();
    for (int i = wid; i < 16; i += 4) {
      int beta = i * 1024 + lane * 16;
      int row = beta >> 8, cb = (beta & 255) ^ ((row & 7) << 4);
      gload16(qb + (size_t)(n0 + row) * (C_ * 2) + cb, lQ + beta);
    }
    for (int i = wid; i < 16; i += 4) {
      int beta = i * 1024 + lane * 16;
      int row = beta >> 7, cb = (beta & 127) ^ ((row & 7) << 4);
      gload16(vb + (size_t)row * (N_ * 2) + n0 * 2 + cb, lV + beta);
    }
    __syncthreads();
    for (int fj = 0; fj < 4; fj++) {
      f32x4 s = z4;
      for (int ks = 0; ks < 4; ks++) {
        int row = fj * 16 + (lane & 15);
        bf16x8 bq_ = *(const bf16x8*)(lQ + row * 256 +
                                      ((ks * 64 + (lane >> 4) * 16) ^ ((row & 7) << 4)));
        s = mfma16(ak[ks], bq_, s);
      }
      float iden = invden[(size_t)bh * N_ + n0 + fj * 16 + (lane & 15)];
      for (int r = 0; r < 4; r++) {
        float pval = __expf(s[r] * kScale) * iden;
        int ml = wid * 16 + (lane >> 4) * 4 + r;
        int nl2 = (fj * 16 + (lane & 15)) * 2;
        *(u16*)(lP + ml * 128 + (nl2 ^ ((ml & 7) << 4))) = f2b(pval);
      }
    }
    __syncthreads();
    for (int ks = 0; ks < 2; ks++) {
      int kb2 = ks * 64 + (lane >> 4) * 16;
      bf16x8 av[2], bp[4];
      for (int fi = 0; fi < 2; fi++) {
        int row = wid * 32 + fi * 16 + (lane & 15);
        av[fi] = *(const bf16x8*)(lV + row * 128 + (kb2 ^ ((row & 7) << 4)));
      }
      for (int fm = 0; fm < 4; fm++) {
        int row = fm * 16 + (lane & 15);
        bp[fm] = *(const bf16x8*)(lP + row * 128 + (kb2 ^ ((row & 7) << 4)));
      }
      for (int fi = 0; fi < 2; fi++)
        for (int fm = 0; fm < 4; fm++)
          oacc[fi][fm] = mfma16(av[fi], bp[fm], oacc[fi][fm]);
    }
  }
  for (int fi = 0; fi < 2; fi++)
    for (int fm = 0; fm < 4; fm++)
      for (int r = 0; r < 4; r++) {
        int d = wid * 32 + fi * 16 + (lane >> 4) * 4 + r;
        int m = fm * 16 + (lane & 15);
        ob[(size_t)d * N_ + m] = oacc[fi][fm][r];
      }
}

// ---------------- gate (3 kernels, parallelized) ----------------
__global__ __launch_bounds__(256) void k_zero_g(float* __restrict__ g) {
  g[blockIdx.x * 256 + threadIdx.x] = 0.f;
}

// grid (N/128, C/128, B): partial dot over 128 channels, atomicAdd into g[b][m]
__global__ __launch_bounds__(256) void k_gate_dot(const float* __restrict__ gw,
                                                  const float* __restrict__ out,
                                                  float* __restrict__ g) {
  __shared__ float part[2][128];
  int b = blockIdx.z, c0 = blockIdx.y * 128, m0 = blockIdx.x * 128;
  int t = threadIdx.x, cp = t >> 7, m = t & 127;
  const float* ob = out + ((size_t)b * C_ + c0) * N_ + m0;
  float a = 0.f;
  for (int c = cp; c < 128; c += 2) a += gw[c0 + c] * ob[(size_t)c * N_ + m];
  part[cp][m] = a;
  __syncthreads();
  if (t < 128) atomicAdd(&g[(size_t)b * N_ + m0 + t], part[0][t] + part[1][t]);
}

// out *= 1 + sigmoid(g[b][n] + gb); float4 elementwise, grid 4096
__global__ __launch_bounds__(256) void k_gate_apply(const float* __restrict__ g,
                                                    const float* __restrict__ gb,
                                                    float* __restrict__ out) {
  size_t i = ((size_t)blockIdx.x * 256 + threadIdx.x) * 4;
  int b = (int)(i / ((size_t)C_ * N_));
  int n = (int)(i & (N_ - 1));
  float4 gv = *(const float4*)(g + (size_t)b * N_ + n);
  float bias = gb[0];
  float4 v = *(float4*)(out + i);
  v.x *= 1.f + 1.f / (1.f + __expf(-(gv.x + bias)));
  v.y *= 1.f + 1.f / (1.f + __expf(-(gv.y + bias)));
  v.z *= 1.f + 1.f / (1.f + __expf(-(gv.z + bias)));
  v.w *= 1.f + 1.f / (1.f + __expf(-(gv.w + bias)));
  *(float4*)(out + i) = v;
}

extern "C" void kernel_launch(void* const* d_in, const int* in_sizes, int n_in,
                              void* d_out, int out_size, void* d_ws, size_t ws_size,
                              hipStream_t stream) {
  const float* x    = (const float*)d_in[0];
  const float* wq   = (const float*)d_in[1];
  const float* bq   = (const float*)d_in[2];
  const float* wk   = (const float*)d_in[3];
  const float* bk   = (const float*)d_in[4];
  const float* wv   = (const float*)d_in[5];
  const float* bv   = (const float*)d_in[6];
  const float* fc1w = (const float*)d_in[7];
  const float* fc1b = (const float*)d_in[8];
  const float* fc2w = (const float*)d_in[9];
  const float* fc2b = (const float*)d_in[10];
  const float* gw   = (const float*)d_in[11];
  const float* gb   = (const float*)d_in[12];
  float* out = (float*)d_out;
  char* ws = (char*)d_ws;

  float* p   = (float*)(ws + OFF_P);
  float* ssc = (float*)(ws + OFF_SS);
  u16* wb  = (u16*)(ws + OFF_WB);
  u16* xt  = (u16*)(ws + OFF_XT);
  u16* qt  = (u16*)(ws + OFF_QT);
  u16* kt  = (u16*)(ws + OFF_KT);
  u16* v   = (u16*)(ws + OFF_V);
  float* den = (float*)(ws + OFF_DEN);
  float* g   = (float*)(ws + OFF_G);

  k_pool<<<B_ * C_, 64, 0, stream>>>(x, p);
  k_castw<<<768, 256, 0, stream>>>(wq, wk, wv, wb);
  k_se<<<B_, 256, 0, stream>>>(p, fc1w, fc1b, fc2w, fc2b, ssc);
  k_zero_g<<<B_ * N_ / 256, 256, 0, stream>>>(g);
  k_xt<<<dim3(16, 8, B_), 256, 0, stream>>>(x, ssc, xt);
  k_qkv<<<dim3(32, B_ * 3), 256, 0, stream>>>(xt, wb, bq, bk, bv, qt, kt, v);
  k_passA<<<dim3(16, 32), 256, 0, stream>>>(qt, kt, den);
  k_passB<<<dim3(16, 32), 256, 0, stream>>>(qt, kt, v, den, out);
  k_gate_dot<<<dim3(N_ / 128, C_ / 128, B_), 256, 0, stream>>>(gw, out, g);
  k_gate_apply<<<B_ * C_ * N_ / 1024, 256, 0, stream>>>(g, gb, out);
}

// Round 3
// 136.303 us; speedup vs baseline: 1.4661x; 1.1071x over previous
//
#include <hip/hip_runtime.h>
#include <hip/hip_bf16.h>

#define B_ 8
#define C_ 512
#define N_ 1024
#define HEADS_ 4
#define DK_ 128
#define R_ 128

typedef float f32x4 __attribute__((ext_vector_type(4)));
typedef __bf16 bf16x8 __attribute__((ext_vector_type(8)));
typedef unsigned short u16;

constexpr float kScale = 0.08838834764831845f; // 1/sqrt(128)

// ---- workspace layout (bytes) ----
#define OFF_P   0u                       // p[B][C] f32            16KB
#define OFF_SS  16384u                   // 1+sigmoid(f) [B][C]    16KB
#define OFF_WB  32768u                   // wq/wk/wv bf16 [3][C][C] 1.5MB
#define OFF_XT  1605632u                 // x1^T [B][N][C] bf16    8MB
#define OFF_QT  9994240u                 // q^T  [B][N][C] bf16    8MB
#define OFF_KT  18382848u                // k^T  [B][N][C] bf16    8MB
#define OFF_V   26771456u                // v    [B][C][N] bf16    8MB
#define OFF_DEN 35160064u                // invden [B*H][N] f32    128KB
#define OFF_G   35291136u                // gate dot [B][N] f32    32KB

__device__ __forceinline__ u16 f2b(float f) {
  __hip_bfloat16 h = __float2bfloat16(f);
  return __builtin_bit_cast(u16, h);
}

typedef const __attribute__((address_space(1))) unsigned int* gptr_t;
typedef __attribute__((address_space(3))) unsigned int* lptr_t;
__device__ __forceinline__ void gload16(const void* g, void* l) {
  __builtin_amdgcn_global_load_lds((gptr_t)g, (lptr_t)l, 16, 0, 0);
}

__device__ __forceinline__ f32x4 mfma16(bf16x8 a, bf16x8 b, f32x4 c) {
  return __builtin_amdgcn_mfma_f32_16x16x32_bf16(a, b, c, 0, 0, 0);
}

// ---------------- pool: p[b][c] = mean_n x[b][c][n] ----------------
__global__ __launch_bounds__(64) void k_pool(const float* __restrict__ x,
                                             float* __restrict__ p) {
  int bc = blockIdx.x, lane = threadIdx.x;
  const float4* row = (const float4*)(x + (size_t)bc * N_);
  float s = 0.f;
  for (int i = lane; i < N_ / 4; i += 64) {
    float4 t = row[i];
    s += t.x + t.y + t.z + t.w;
  }
  for (int o = 32; o > 0; o >>= 1) s += __shfl_down(s, o, 64);
  if (lane == 0) p[bc] = s * (1.0f / N_);
}

// ---------------- SE MLP: sscale = 1 + sigmoid(fc2(relu(fc1(p)))) ----------------
__global__ __launch_bounds__(256) void k_se(const float* __restrict__ p,
                                            const float* __restrict__ fc1w,
                                            const float* __restrict__ fc1b,
                                            const float* __restrict__ fc2w,
                                            const float* __restrict__ fc2b,
                                            float* __restrict__ ss) {
  __shared__ float pl[C_];
  __shared__ float f1[R_];
  int b = blockIdx.x, t = threadIdx.x;
  for (int c = t; c < C_; c += 256) pl[c] = p[b * C_ + c];
  __syncthreads();
  if (t < R_) {
    float a = fc1b[t];
    for (int c = 0; c < C_; c++) a += pl[c] * fc1w[t * C_ + c];
    f1[t] = fmaxf(a, 0.f);
  }
  __syncthreads();
  for (int c = t; c < C_; c += 256) {
    float a = fc2b[c];
    for (int j = 0; j < R_; j++) a += f1[j] * fc2w[c * R_ + j];
    ss[b * C_ + c] = 1.f + 1.f / (1.f + __expf(-a));
  }
}

// ---------------- cast weights to bf16 ----------------
__global__ __launch_bounds__(256) void k_castw(const float* __restrict__ wq,
                                               const float* __restrict__ wk,
                                               const float* __restrict__ wv,
                                               u16* __restrict__ wb) {
  int i = blockIdx.x * 256 + threadIdx.x;
  int idx = i * 4;
  const float* srcs[3] = {wq, wk, wv};
  int w = idx / (C_ * C_), off = idx % (C_ * C_);
  float4 v = *(const float4*)(srcs[w] + off);
  u16* d = wb + idx;
  d[0] = f2b(v.x); d[1] = f2b(v.y); d[2] = f2b(v.z); d[3] = f2b(v.w);
}

// ---------------- x1^T[b][n][c] = bf16(x[b][c][n] * ss[b][c]) ----------------
__global__ __launch_bounds__(256) void k_xt(const float* __restrict__ x,
                                            const float* __restrict__ ss,
                                            u16* __restrict__ xt) {
  int b = blockIdx.z, c0 = blockIdx.y * 64, n0 = blockIdx.x * 64;
  __shared__ float tile[64][65];
  int t = threadIdx.x;
  int cr = t >> 4, nc4 = (t & 15) * 4;
  for (int j = 0; j < 4; j++) {
    int c = cr + j * 16;
    float sc = ss[b * C_ + c0 + c];
    float4 v = *(const float4*)(x + ((size_t)b * C_ + c0 + c) * N_ + n0 + nc4);
    tile[c][nc4 + 0] = v.x * sc;
    tile[c][nc4 + 1] = v.y * sc;
    tile[c][nc4 + 2] = v.z * sc;
    tile[c][nc4 + 3] = v.w * sc;
  }
  __syncthreads();
  int nr = t >> 2, cc = (t & 3) * 16;
  u16 ov[16];
  for (int m = 0; m < 16; m++) ov[m] = f2b(tile[cc + m][nr]);
  u16* dst = xt + ((size_t)b * N_ + n0 + nr) * C_ + c0 + cc;
  for (int m = 0; m < 16; m++) dst[m] = ov[m];
}

// ---------------- QKV GEMM (bf16 MFMA, 128x128 tile, BK=64) ----------------
__global__ __launch_bounds__(256) void k_qkv(const u16* __restrict__ xt,
                                             const u16* __restrict__ wb,
                                             const float* __restrict__ bq,
                                             const float* __restrict__ bk,
                                             const float* __restrict__ bv,
                                             u16* __restrict__ qt,
                                             u16* __restrict__ kt,
                                             u16* __restrict__ v) {
  __shared__ char smem[32768];
  int b = blockIdx.y / 3, sel = blockIdx.y % 3;
  int tile = blockIdx.x;
  const char *Ab, *Bb;
  u16* out;
  const float* bias;
  int mt, nt, rstride;
  size_t xtoff = (size_t)b * N_ * C_;
  if (sel < 2) {
    mt = tile & 7; nt = tile >> 3;
    Ab = (const char*)(xt + xtoff + (size_t)mt * 128 * C_);
    Bb = (const char*)(wb + (size_t)sel * C_ * C_ + (size_t)nt * 128 * C_);
    out = (sel ? kt : qt) + xtoff;
    bias = sel ? bk : bq;
    rstride = C_ * 2;
  } else {
    mt = tile & 3; nt = tile >> 2;
    Ab = (const char*)(wb + (size_t)2 * C_ * C_ + (size_t)mt * 128 * C_);
    Bb = (const char*)(xt + xtoff + (size_t)nt * 128 * C_);
    out = v + (size_t)b * C_ * N_;
    bias = bv;
    rstride = N_ * 2;
  }
  int t = threadIdx.x, lane = t & 63, wid = t >> 6;
  int wr = wid >> 1, wc = wid & 1;
  const f32x4 z4 = {0.f, 0.f, 0.f, 0.f};
  f32x4 acc[4][4];
  for (int i = 0; i < 4; i++)
    for (int j = 0; j < 4; j++) acc[i][j] = z4;

  char* lA = smem;
  char* lB = smem + 16384;
  for (int ko = 0; ko < C_; ko += 64) {
    __syncthreads();
    for (int i = wid; i < 16; i += 4) {
      int beta = i * 1024 + lane * 16;
      int row = beta >> 7, cb = (beta & 127) ^ ((row & 7) << 4);
      gload16(Ab + (size_t)row * 1024 + ko * 2 + cb, lA + beta);
    }
    for (int i = wid; i < 16; i += 4) {
      int beta = i * 1024 + lane * 16;
      int row = beta >> 7, cb = (beta & 127) ^ ((row & 7) << 4);
      gload16(Bb + (size_t)row * 1024 + ko * 2 + cb, lB + beta);
    }
    __syncthreads();
    for (int ks = 0; ks < 2; ks++) {
      int kb = ks * 64 + (lane >> 4) * 16;
      bf16x8 af[4], bfr[4];
      for (int fi = 0; fi < 4; fi++) {
        int row = wr * 64 + fi * 16 + (lane & 15);
        af[fi] = *(const bf16x8*)(lA + row * 128 + (kb ^ ((row & 7) << 4)));
      }
      for (int fj = 0; fj < 4; fj++) {
        int row = wc * 64 + fj * 16 + (lane & 15);
        bfr[fj] = *(const bf16x8*)(lB + row * 128 + (kb ^ ((row & 7) << 4)));
      }
      for (int fi = 0; fi < 4; fi++)
        for (int fj = 0; fj < 4; fj++)
          acc[fi][fj] = mfma16(af[fi], bfr[fj], acc[fi][fj]);
    }
  }
  __syncthreads();
  for (int fi = 0; fi < 4; fi++)
    for (int fj = 0; fj < 4; fj++) {
      int colb = wc * 64 + fj * 16 + (lane & 15);
      for (int r = 0; r < 4; r++) {
        int rowb = wr * 64 + fi * 16 + (lane >> 4) * 4 + r;
        float bva = (sel < 2) ? bias[nt * 128 + colb] : bias[mt * 128 + rowb];
        float val = acc[fi][fj][r] + bva;
        int byte = rowb * 256 + ((colb * 2) ^ ((rowb & 7) << 4));
        *(u16*)(smem + byte) = f2b(val);
      }
    }
  __syncthreads();
  for (int i = t; i < 2048; i += 256) {
    int row = i >> 4, cb = (i & 15) * 16;
    bf16x8 val = *(const bf16x8*)(smem + row * 256 + (cb ^ ((row & 7) << 4)));
    *(bf16x8*)((char*)out + (size_t)(mt * 128 + row) * rstride + nt * 256 + cb) = val;
  }
}

// ---------------- pass A: invden[bh][n] = 1/sum_m exp(scale*S[n,m]) ----------------
// 128 q-rows per block; 2 row-groups share every B-fragment ds_read.
__global__ __launch_bounds__(256) void k_passA(const u16* __restrict__ qt,
                                               const u16* __restrict__ kt,
                                               float* __restrict__ invden) {
  __shared__ char lK[32768]; // [128 m][128 d] swizzled
  int nb = blockIdx.x * 128, bh = blockIdx.y;
  int b = bh >> 2, h = bh & 3;
  const char* qb = (const char*)(qt + (size_t)b * N_ * C_ + h * DK_);
  const char* kb = (const char*)(kt + (size_t)b * N_ * C_ + h * DK_);
  int t = threadIdx.x, lane = t & 63, wid = t >> 6;
  bf16x8 aq[2][4];
  for (int g = 0; g < 2; g++) {
    const char* qr = qb + (size_t)(nb + wid * 32 + g * 16 + (lane & 15)) * (C_ * 2);
    for (int ks = 0; ks < 4; ks++)
      aq[g][ks] = *(const bf16x8*)(qr + ks * 64 + (lane >> 4) * 16);
  }
  float sacc[2][4] = {{0.f, 0.f, 0.f, 0.f}, {0.f, 0.f, 0.f, 0.f}};
  const f32x4 z4 = {0.f, 0.f, 0.f, 0.f};
  for (int mc = 0; mc < 8; mc++) {
    __syncthreads();
    for (int i = wid; i < 32; i += 4) {
      int beta = i * 1024 + lane * 16;
      int row = beta >> 8, cb = (beta & 255) ^ ((row & 7) << 4);
      gload16(kb + (size_t)(mc * 128 + row) * (C_ * 2) + cb, lK + beta);
    }
    __syncthreads();
    for (int fj = 0; fj < 8; fj++) {
      f32x4 s0 = z4, s1 = z4;
      for (int ks = 0; ks < 4; ks++) {
        int row = fj * 16 + (lane & 15);
        bf16x8 bk_ = *(const bf16x8*)(lK + row * 256 +
                                      ((ks * 64 + (lane >> 4) * 16) ^ ((row & 7) << 4)));
        s0 = mfma16(aq[0][ks], bk_, s0);
        s1 = mfma16(aq[1][ks], bk_, s1);
      }
      for (int r = 0; r < 4; r++) {
        sacc[0][r] += __expf(s0[r] * kScale);
        sacc[1][r] += __expf(s1[r] * kScale);
      }
    }
  }
  for (int g = 0; g < 2; g++)
    for (int r = 0; r < 4; r++) {
      float vv = sacc[g][r];
      for (int m = 1; m < 16; m <<= 1) vv += __shfl_xor(vv, m, 64);
      sacc[g][r] = vv;
    }
  if ((lane & 15) == 0) {
    for (int g = 0; g < 2; g++) {
      int n = nb + wid * 32 + g * 16 + (lane >> 4) * 4;
      for (int r = 0; r < 4; r++) invden[(size_t)bh * N_ + n + r] = 1.f / sacc[g][r];
    }
  }
}

// ---------------- pass B: o[d][m] + fused gate partial dot ----------------
// 128 m-cols per block; 2 m-groups share S^T B-fragments; PV over full 128 m.
__global__ __launch_bounds__(256) void k_passB(const u16* __restrict__ qt,
                                               const u16* __restrict__ kt,
                                               const u16* __restrict__ v,
                                               const float* __restrict__ invden,
                                               const float* __restrict__ gw,
                                               float* __restrict__ out,
                                               float* __restrict__ g) {
  __shared__ char lQ[16384]; // [64 n][128 d] swz
  __shared__ char lV[16384]; // [128 d][64 n] swz
  __shared__ char lP[32768]; // [128 m][64 n] bf16 swz (16KB used, pad for safety)
  __shared__ float gacc[128];
  int mb = blockIdx.x * 128, bh = blockIdx.y;
  int b = bh >> 2, h = bh & 3;
  const char* qb = (const char*)(qt + (size_t)b * N_ * C_ + h * DK_);
  const char* kb = (const char*)(kt + (size_t)b * N_ * C_ + h * DK_);
  const char* vb = (const char*)(v + ((size_t)b * C_ + h * DK_) * N_);
  float* ob = out + ((size_t)b * C_ + h * DK_) * N_ + mb;
  int t = threadIdx.x, lane = t & 63, wid = t >> 6;
  bf16x8 ak[2][4];
  for (int gi = 0; gi < 2; gi++) {
    const char* kr = kb + (size_t)(mb + wid * 32 + gi * 16 + (lane & 15)) * (C_ * 2);
    for (int ks = 0; ks < 4; ks++)
      ak[gi][ks] = *(const bf16x8*)(kr + ks * 64 + (lane >> 4) * 16);
  }
  if (t < 128) gacc[t] = 0.f;
  const f32x4 z4 = {0.f, 0.f, 0.f, 0.f};
  f32x4 oacc[2][8];
  for (int i = 0; i < 2; i++)
    for (int j = 0; j < 8; j++) oacc[i][j] = z4;

  for (int nc = 0; nc < 16; nc++) {
    int n0 = nc * 64;
    __syncthreads();
    for (int i = wid; i < 16; i += 4) {
      int beta = i * 1024 + lane * 16;
      int row = beta >> 8, cb = (beta & 255) ^ ((row & 7) << 4);
      gload16(qb + (size_t)(n0 + row) * (C_ * 2) + cb, lQ + beta);
    }
    for (int i = wid; i < 16; i += 4) {
      int beta = i * 1024 + lane * 16;
      int row = beta >> 7, cb = (beta & 127) ^ ((row & 7) << 4);
      gload16(vb + (size_t)row * (N_ * 2) + n0 * 2 + cb, lV + beta);
    }
    __syncthreads();
    // S^T [128 m][64 n] + P = exp(scale*S)*invden[n] -> lP (bf16)
    for (int fj = 0; fj < 4; fj++) {
      f32x4 s0 = z4, s1 = z4;
      for (int ks = 0; ks < 4; ks++) {
        int row = fj * 16 + (lane & 15);
        bf16x8 bq_ = *(const bf16x8*)(lQ + row * 256 +
                                      ((ks * 64 + (lane >> 4) * 16) ^ ((row & 7) << 4)));
        s0 = mfma16(ak[0][ks], bq_, s0);
        s1 = mfma16(ak[1][ks], bq_, s1);
      }
      float iden = invden[(size_t)bh * N_ + n0 + fj * 16 + (lane & 15)];
      int nl2 = (fj * 16 + (lane & 15)) * 2;
      for (int r = 0; r < 4; r++) {
        float p0 = __expf(s0[r] * kScale) * iden;
        float p1 = __expf(s1[r] * kScale) * iden;
        int ml0 = wid * 32 + (lane >> 4) * 4 + r;
        int ml1 = ml0 + 16;
        *(u16*)(lP + ml0 * 128 + (nl2 ^ ((ml0 & 7) << 4))) = f2b(p0);
        *(u16*)(lP + ml1 * 128 + (nl2 ^ ((ml1 & 7) << 4))) = f2b(p1);
      }
    }
    __syncthreads();
    // PV: wave owns d rows [32w,32w+32), all 128 m cols
    for (int ks2 = 0; ks2 < 2; ks2++) {
      int kb2 = ks2 * 64 + (lane >> 4) * 16;
      bf16x8 av[2], bp[8];
      for (int fi = 0; fi < 2; fi++) {
        int row = wid * 32 + fi * 16 + (lane & 15);
        av[fi] = *(const bf16x8*)(lV + row * 128 + (kb2 ^ ((row & 7) << 4)));
      }
      for (int fm = 0; fm < 8; fm++) {
        int row = fm * 16 + (lane & 15);
        bp[fm] = *(const bf16x8*)(lP + row * 128 + (kb2 ^ ((row & 7) << 4)));
      }
      for (int fi = 0; fi < 2; fi++)
        for (int fm = 0; fm < 8; fm++)
          oacc[fi][fm] = mfma16(av[fi], bp[fm], oacc[fi][fm]);
    }
  }
  // epilogue: store o + fused gate partial (sum_d gw[c]*o[c][m])
  float gwl[2][4];
  for (int fi = 0; fi < 2; fi++)
    for (int r = 0; r < 4; r++)
      gwl[fi][r] = gw[h * DK_ + wid * 32 + fi * 16 + (lane >> 4) * 4 + r];
  __syncthreads(); // gacc zero-init visible
  for (int fm = 0; fm < 8; fm++) {
    int m = fm * 16 + (lane & 15);
    float part = 0.f;
    for (int fi = 0; fi < 2; fi++) {
      int d = wid * 32 + fi * 16 + (lane >> 4) * 4;
      for (int r = 0; r < 4; r++) {
        float val = oacc[fi][fm][r];
        ob[(size_t)(d + r) * N_ + m] = val;
        part += gwl[fi][r] * val;
      }
    }
    atomicAdd(&gacc[m], part);
  }
  __syncthreads();
  if (t < 128) atomicAdd(&g[(size_t)b * N_ + mb + t], gacc[t]);
}

// ---------------- gate finish ----------------
__global__ __launch_bounds__(256) void k_zero_g(float* __restrict__ g) {
  g[blockIdx.x * 256 + threadIdx.x] = 0.f;
}

__global__ __launch_bounds__(256) void k_gate_apply(const float* __restrict__ g,
                                                    const float* __restrict__ gb,
                                                    float* __restrict__ out) {
  size_t i = ((size_t)blockIdx.x * 256 + threadIdx.x) * 4;
  int b = (int)(i / ((size_t)C_ * N_));
  int n = (int)(i & (N_ - 1));
  float4 gv = *(const float4*)(g + (size_t)b * N_ + n);
  float bias = gb[0];
  float4 v = *(float4*)(out + i);
  v.x *= 1.f + 1.f / (1.f + __expf(-(gv.x + bias)));
  v.y *= 1.f + 1.f / (1.f + __expf(-(gv.y + bias)));
  v.z *= 1.f + 1.f / (1.f + __expf(-(gv.z + bias)));
  v.w *= 1.f + 1.f / (1.f + __expf(-(gv.w + bias)));
  *(float4*)(out + i) = v;
}

extern "C" void kernel_launch(void* const* d_in, const int* in_sizes, int n_in,
                              void* d_out, int out_size, void* d_ws, size_t ws_size,
                              hipStream_t stream) {
  const float* x    = (const float*)d_in[0];
  const float* wq   = (const float*)d_in[1];
  const float* bq   = (const float*)d_in[2];
  const float* wk   = (const float*)d_in[3];
  const float* bk   = (const float*)d_in[4];
  const float* wv   = (const float*)d_in[5];
  const float* bv   = (const float*)d_in[6];
  const float* fc1w = (const float*)d_in[7];
  const float* fc1b = (const float*)d_in[8];
  const float* fc2w = (const float*)d_in[9];
  const float* fc2b = (const float*)d_in[10];
  const float* gw   = (const float*)d_in[11];
  const float* gb   = (const float*)d_in[12];
  float* out = (float*)d_out;
  char* ws = (char*)d_ws;

  float* p   = (float*)(ws + OFF_P);
  float* ssc = (float*)(ws + OFF_SS);
  u16* wb  = (u16*)(ws + OFF_WB);
  u16* xt  = (u16*)(ws + OFF_XT);
  u16* qt  = (u16*)(ws + OFF_QT);
  u16* kt  = (u16*)(ws + OFF_KT);
  u16* v   = (u16*)(ws + OFF_V);
  float* den = (float*)(ws + OFF_DEN);
  float* g   = (float*)(ws + OFF_G);

  k_pool<<<B_ * C_, 64, 0, stream>>>(x, p);
  k_castw<<<768, 256, 0, stream>>>(wq, wk, wv, wb);
  k_se<<<B_, 256, 0, stream>>>(p, fc1w, fc1b, fc2w, fc2b, ssc);
  k_zero_g<<<B_ * N_ / 256, 256, 0, stream>>>(g);
  k_xt<<<dim3(16, 8, B_), 256, 0, stream>>>(x, ssc, xt);
  k_qkv<<<dim3(32, B_ * 3), 256, 0, stream>>>(xt, wb, bq, bk, bv, qt, kt, v);
  k_passA<<<dim3(8, 32), 256, 0, stream>>>(qt, kt, den);
  k_passB<<<dim3(8, 32), 256, 0, stream>>>(qt, kt, v, den, gw, out, g);
  k_gate_apply<<<B_ * C_ * N_ / 1024, 256, 0, stream>>>(g, gb, out);
}

// Round 4
// 124.710 us; speedup vs baseline: 1.6024x; 1.0930x over previous
//
#include <hip/hip_runtime.h>
#include <hip/hip_bf16.h>

#define B_ 8
#define C_ 512
#define N_ 1024
#define HEADS_ 4
#define DK_ 128
#define R_ 128

typedef float f32x4 __attribute__((ext_vector_type(4)));
typedef __bf16 bf16x8 __attribute__((ext_vector_type(8)));
typedef unsigned short u16;

constexpr float kScale = 0.08838834764831845f; // 1/sqrt(128)

// ---- workspace layout (bytes) ----
#define OFF_P   0u                       // p[B][C] f32            16KB
#define OFF_SS  16384u                   // 1+sigmoid(f) [B][C]    16KB
#define OFF_WB  32768u                   // wq/wk/wv bf16 [3][C][C] 1.5MB
#define OFF_XT  1605632u                 // x1^T [B][N][C] bf16    8MB
#define OFF_QT  9994240u                 // q^T  [B][N][C] bf16    8MB
#define OFF_KT  18382848u                // k^T  [B][N][C] bf16    8MB
#define OFF_V   26771456u                // v    [B][C][N] bf16    8MB
#define OFF_DEN 35160064u                // invden [B*H][N] f32    128KB
#define OFF_G   35291136u                // gate dot [B][N] f32    32KB

__device__ __forceinline__ u16 f2b(float f) {
  __hip_bfloat16 h = __float2bfloat16(f);
  return __builtin_bit_cast(u16, h);
}

typedef const __attribute__((address_space(1))) unsigned int* gptr_t;
typedef __attribute__((address_space(3))) unsigned int* lptr_t;
__device__ __forceinline__ void gload16(const void* g, void* l) {
  __builtin_amdgcn_global_load_lds((gptr_t)g, (lptr_t)l, 16, 0, 0);
}

__device__ __forceinline__ f32x4 mfma16(bf16x8 a, bf16x8 b, f32x4 c) {
  return __builtin_amdgcn_mfma_f32_16x16x32_bf16(a, b, c, 0, 0, 0);
}

// ---------------- pool: p[b][c] = mean_n x[b][c][n] ----------------
__global__ __launch_bounds__(64) void k_pool(const float* __restrict__ x,
                                             float* __restrict__ p) {
  int bc = blockIdx.x, lane = threadIdx.x;
  const float4* row = (const float4*)(x + (size_t)bc * N_);
  float s = 0.f;
  for (int i = lane; i < N_ / 4; i += 64) {
    float4 t = row[i];
    s += t.x + t.y + t.z + t.w;
  }
  for (int o = 32; o > 0; o >>= 1) s += __shfl_down(s, o, 64);
  if (lane == 0) p[bc] = s * (1.0f / N_);
}

// ---------------- SE MLP: sscale = 1 + sigmoid(fc2(relu(fc1(p)))) ----------------
__global__ __launch_bounds__(256) void k_se(const float* __restrict__ p,
                                            const float* __restrict__ fc1w,
                                            const float* __restrict__ fc1b,
                                            const float* __restrict__ fc2w,
                                            const float* __restrict__ fc2b,
                                            float* __restrict__ ss) {
  __shared__ float pl[C_];
  __shared__ float f1[R_];
  int b = blockIdx.x, t = threadIdx.x;
  for (int c = t; c < C_; c += 256) pl[c] = p[b * C_ + c];
  __syncthreads();
  if (t < R_) {
    float a = fc1b[t];
    for (int c = 0; c < C_; c++) a += pl[c] * fc1w[t * C_ + c];
    f1[t] = fmaxf(a, 0.f);
  }
  __syncthreads();
  for (int c = t; c < C_; c += 256) {
    float a = fc2b[c];
    for (int j = 0; j < R_; j++) a += f1[j] * fc2w[c * R_ + j];
    ss[b * C_ + c] = 1.f + 1.f / (1.f + __expf(-a));
  }
}

// ---------------- cast weights to bf16 ----------------
__global__ __launch_bounds__(256) void k_castw(const float* __restrict__ wq,
                                               const float* __restrict__ wk,
                                               const float* __restrict__ wv,
                                               u16* __restrict__ wb) {
  int i = blockIdx.x * 256 + threadIdx.x;
  int idx = i * 4;
  const float* srcs[3] = {wq, wk, wv};
  int w = idx / (C_ * C_), off = idx % (C_ * C_);
  float4 v = *(const float4*)(srcs[w] + off);
  u16* d = wb + idx;
  d[0] = f2b(v.x); d[1] = f2b(v.y); d[2] = f2b(v.z); d[3] = f2b(v.w);
}

// ---------------- x1^T[b][n][c] = bf16(x[b][c][n] * ss[b][c]) ----------------
__global__ __launch_bounds__(256) void k_xt(const float* __restrict__ x,
                                            const float* __restrict__ ss,
                                            u16* __restrict__ xt) {
  int b = blockIdx.z, c0 = blockIdx.y * 64, n0 = blockIdx.x * 64;
  __shared__ float tile[64][65];
  int t = threadIdx.x;
  int cr = t >> 4, nc4 = (t & 15) * 4;
  for (int j = 0; j < 4; j++) {
    int c = cr + j * 16;
    float sc = ss[b * C_ + c0 + c];
    float4 v = *(const float4*)(x + ((size_t)b * C_ + c0 + c) * N_ + n0 + nc4);
    tile[c][nc4 + 0] = v.x * sc;
    tile[c][nc4 + 1] = v.y * sc;
    tile[c][nc4 + 2] = v.z * sc;
    tile[c][nc4 + 3] = v.w * sc;
  }
  __syncthreads();
  int nr = t >> 2, cc = (t & 3) * 16;
  u16 ov[16];
  for (int m = 0; m < 16; m++) ov[m] = f2b(tile[cc + m][nr]);
  u16* dst = xt + ((size_t)b * N_ + n0 + nr) * C_ + c0 + cc;
  for (int m = 0; m < 16; m++) dst[m] = ov[m];
}

// ---------------- QKV GEMM (bf16 MFMA, 128x128 tile, BK=64) ----------------
__global__ __launch_bounds__(256) void k_qkv(const u16* __restrict__ xt,
                                             const u16* __restrict__ wb,
                                             const float* __restrict__ bq,
                                             const float* __restrict__ bk,
                                             const float* __restrict__ bv,
                                             u16* __restrict__ qt,
                                             u16* __restrict__ kt,
                                             u16* __restrict__ v) {
  __shared__ char smem[32768];
  int b = blockIdx.y / 3, sel = blockIdx.y % 3;
  int tile = blockIdx.x;
  const char *Ab, *Bb;
  u16* out;
  const float* bias;
  int mt, nt, rstride;
  size_t xtoff = (size_t)b * N_ * C_;
  if (sel < 2) {
    mt = tile & 7; nt = tile >> 3;
    Ab = (const char*)(xt + xtoff + (size_t)mt * 128 * C_);
    Bb = (const char*)(wb + (size_t)sel * C_ * C_ + (size_t)nt * 128 * C_);
    out = (sel ? kt : qt) + xtoff;
    bias = sel ? bk : bq;
    rstride = C_ * 2;
  } else {
    mt = tile & 3; nt = tile >> 2;
    Ab = (const char*)(wb + (size_t)2 * C_ * C_ + (size_t)mt * 128 * C_);
    Bb = (const char*)(xt + xtoff + (size_t)nt * 128 * C_);
    out = v + (size_t)b * C_ * N_;
    bias = bv;
    rstride = N_ * 2;
  }
  int t = threadIdx.x, lane = t & 63, wid = t >> 6;
  int wr = wid >> 1, wc = wid & 1;
  const f32x4 z4 = {0.f, 0.f, 0.f, 0.f};
  f32x4 acc[4][4];
  for (int i = 0; i < 4; i++)
    for (int j = 0; j < 4; j++) acc[i][j] = z4;

  char* lA = smem;
  char* lB = smem + 16384;
  for (int ko = 0; ko < C_; ko += 64) {
    __syncthreads();
    for (int i = wid; i < 16; i += 4) {
      int beta = i * 1024 + lane * 16;
      int row = beta >> 7, cb = (beta & 127) ^ ((row & 7) << 4);
      gload16(Ab + (size_t)row * 1024 + ko * 2 + cb, lA + beta);
    }
    for (int i = wid; i < 16; i += 4) {
      int beta = i * 1024 + lane * 16;
      int row = beta >> 7, cb = (beta & 127) ^ ((row & 7) << 4);
      gload16(Bb + (size_t)row * 1024 + ko * 2 + cb, lB + beta);
    }
    __syncthreads();
    for (int ks = 0; ks < 2; ks++) {
      int kb = ks * 64 + (lane >> 4) * 16;
      bf16x8 af[4], bfr[4];
      for (int fi = 0; fi < 4; fi++) {
        int row = wr * 64 + fi * 16 + (lane & 15);
        af[fi] = *(const bf16x8*)(lA + row * 128 + (kb ^ ((row & 7) << 4)));
      }
      for (int fj = 0; fj < 4; fj++) {
        int row = wc * 64 + fj * 16 + (lane & 15);
        bfr[fj] = *(const bf16x8*)(lB + row * 128 + (kb ^ ((row & 7) << 4)));
      }
      for (int fi = 0; fi < 4; fi++)
        for (int fj = 0; fj < 4; fj++)
          acc[fi][fj] = mfma16(af[fi], bfr[fj], acc[fi][fj]);
    }
  }
  __syncthreads();
  for (int fi = 0; fi < 4; fi++)
    for (int fj = 0; fj < 4; fj++) {
      int colb = wc * 64 + fj * 16 + (lane & 15);
      for (int r = 0; r < 4; r++) {
        int rowb = wr * 64 + fi * 16 + (lane >> 4) * 4 + r;
        float bva = (sel < 2) ? bias[nt * 128 + colb] : bias[mt * 128 + rowb];
        float val = acc[fi][fj][r] + bva;
        int byte = rowb * 256 + ((colb * 2) ^ ((rowb & 7) << 4));
        *(u16*)(smem + byte) = f2b(val);
      }
    }
  __syncthreads();
  for (int i = t; i < 2048; i += 256) {
    int row = i >> 4, cb = (i & 15) * 16;
    bf16x8 val = *(const bf16x8*)(smem + row * 256 + (cb ^ ((row & 7) << 4)));
    *(bf16x8*)((char*)out + (size_t)(mt * 128 + row) * rstride + nt * 256 + cb) = val;
  }
}

// ---------------- pass A: invden[bh][n] = 1/sum_m exp(scale*S[n,m]) ----------------
// 8 waves x 16 q-rows; double-buffered K tile with early-issue prefetch;
// grid (bh, nb-tile) so same-bh blocks share an XCD L2.
__global__ __launch_bounds__(512) void k_passA(const u16* __restrict__ qt,
                                               const u16* __restrict__ kt,
                                               float* __restrict__ invden) {
  __shared__ char lK[2][32768]; // [128 m][128 d] swizzled, x2
  int bh = blockIdx.x, nb = blockIdx.y * 128;
  int b = bh >> 2, h = bh & 3;
  const char* qb = (const char*)(qt + (size_t)b * N_ * C_ + h * DK_);
  const char* kb = (const char*)(kt + (size_t)b * N_ * C_ + h * DK_);
  int t = threadIdx.x, lane = t & 63, wid = t >> 6; // wid 0..7
  bf16x8 aq[4];
  {
    const char* qr = qb + (size_t)(nb + wid * 16 + (lane & 15)) * (C_ * 2);
    for (int ks = 0; ks < 4; ks++)
      aq[ks] = *(const bf16x8*)(qr + ks * 64 + (lane >> 4) * 16);
  }
  float sacc[4] = {0.f, 0.f, 0.f, 0.f};
  const f32x4 z4 = {0.f, 0.f, 0.f, 0.f};
  // prologue: stage chunk 0
  for (int i = wid; i < 32; i += 8) {
    int beta = i * 1024 + lane * 16;
    int row = beta >> 8, cb = (beta & 255) ^ ((row & 7) << 4);
    gload16(kb + (size_t)row * (C_ * 2) + cb, lK[0] + beta);
  }
  for (int mc = 0; mc < 8; mc++) {
    int cur = mc & 1;
    __syncthreads(); // drains vmcnt: lK[cur] staged; prior reads done
    if (mc < 7) {
      int mnext = (mc + 1) * 128;
      for (int i = wid; i < 32; i += 8) {
        int beta = i * 1024 + lane * 16;
        int row = beta >> 8, cb = (beta & 255) ^ ((row & 7) << 4);
        gload16(kb + (size_t)(mnext + row) * (C_ * 2) + cb, lK[cur ^ 1] + beta);
      }
    }
    for (int fj = 0; fj < 8; fj++) {
      f32x4 s = z4;
      for (int ks = 0; ks < 4; ks++) {
        int row = fj * 16 + (lane & 15);
        bf16x8 bk_ = *(const bf16x8*)(lK[cur] + row * 256 +
                                      ((ks * 64 + (lane >> 4) * 16) ^ ((row & 7) << 4)));
        s = mfma16(aq[ks], bk_, s);
      }
      for (int r = 0; r < 4; r++) sacc[r] += __expf(s[r] * kScale);
    }
  }
  for (int r = 0; r < 4; r++) {
    float vv = sacc[r];
    for (int m = 1; m < 16; m <<= 1) vv += __shfl_xor(vv, m, 64);
    sacc[r] = vv;
  }
  if ((lane & 15) == 0) {
    int n = nb + wid * 16 + (lane >> 4) * 4;
    for (int r = 0; r < 4; r++) invden[(size_t)bh * N_ + n + r] = 1.f / sacc[r];
  }
}

// ---------------- pass B: o[d][m] + fused gate partial dot ----------------
// 8 waves; double-buffered Q/V staging w/ early-issue prefetch; raw mid-barrier
// (no vmcnt drain) between softmax-write and PV; grid (bh, m-tile) for XCD L2.
__global__ __launch_bounds__(512) void k_passB(const u16* __restrict__ qt,
                                               const u16* __restrict__ kt,
                                               const u16* __restrict__ v,
                                               const float* __restrict__ invden,
                                               const float* __restrict__ gw,
                                               float* __restrict__ out,
                                               float* __restrict__ g) {
  __shared__ char lQ[2][16384]; // [64 n][128 d] swz, x2
  __shared__ char lV[2][16384]; // [128 d][64 n] swz, x2
  __shared__ char lP[16384];    // [128 m][64 n] bf16 swz
  __shared__ float gacc[128];
  int bh = blockIdx.x, mb = blockIdx.y * 128;
  int b = bh >> 2, h = bh & 3;
  const char* qb = (const char*)(qt + (size_t)b * N_ * C_ + h * DK_);
  const char* kb = (const char*)(kt + (size_t)b * N_ * C_ + h * DK_);
  const char* vb = (const char*)(v + ((size_t)b * C_ + h * DK_) * N_);
  float* ob = out + ((size_t)b * C_ + h * DK_) * N_ + mb;
  int t = threadIdx.x, lane = t & 63, wid = t >> 6; // wid 0..7
  bf16x8 ak[4]; // wave's 16 m-rows
  {
    const char* kr = kb + (size_t)(mb + wid * 16 + (lane & 15)) * (C_ * 2);
    for (int ks = 0; ks < 4; ks++)
      ak[ks] = *(const bf16x8*)(kr + ks * 64 + (lane >> 4) * 16);
  }
  if (t < 128) gacc[t] = 0.f;
  const f32x4 z4 = {0.f, 0.f, 0.f, 0.f};
  f32x4 oacc[8];
  for (int j = 0; j < 8; j++) oacc[j] = z4;

  // prologue: stage chunk 0 into buf 0
  for (int i = wid; i < 16; i += 8) {
    int beta = i * 1024 + lane * 16;
    int row = beta >> 8, cb = (beta & 255) ^ ((row & 7) << 4);
    gload16(qb + (size_t)row * (C_ * 2) + cb, lQ[0] + beta);
  }
  for (int i = wid; i < 16; i += 8) {
    int beta = i * 1024 + lane * 16;
    int row = beta >> 7, cb = (beta & 127) ^ ((row & 7) << 4);
    gload16(vb + (size_t)row * (N_ * 2) + cb, lV[0] + beta);
  }

  for (int nc = 0; nc < 16; nc++) {
    int n0 = nc * 64, cur = nc & 1;
    __syncthreads(); // drains vmcnt: buf[cur] staged; prior chunk's LDS reads done
    if (nc < 15) {
      int nn = n0 + 64;
      for (int i = wid; i < 16; i += 8) {
        int beta = i * 1024 + lane * 16;
        int row = beta >> 8, cb = (beta & 255) ^ ((row & 7) << 4);
        gload16(qb + (size_t)(nn + row) * (C_ * 2) + cb, lQ[cur ^ 1] + beta);
      }
      for (int i = wid; i < 16; i += 8) {
        int beta = i * 1024 + lane * 16;
        int row = beta >> 7, cb = (beta & 127) ^ ((row & 7) << 4);
        gload16(vb + (size_t)row * (N_ * 2) + nn * 2 + cb, lV[cur ^ 1] + beta);
      }
    }
    // S^T phase: wave's 16 m-rows x 64 n
    for (int fj = 0; fj < 4; fj++) {
      f32x4 s = z4;
      for (int ks = 0; ks < 4; ks++) {
        int row = fj * 16 + (lane & 15);
        bf16x8 bq_ = *(const bf16x8*)(lQ[cur] + row * 256 +
                                      ((ks * 64 + (lane >> 4) * 16) ^ ((row & 7) << 4)));
        s = mfma16(ak[ks], bq_, s);
      }
      float iden = invden[(size_t)bh * N_ + n0 + fj * 16 + (lane & 15)];
      int nl2 = (fj * 16 + (lane & 15)) * 2;
      for (int r = 0; r < 4; r++) {
        float pval = __expf(s[r] * kScale) * iden;
        int ml = wid * 16 + (lane >> 4) * 4 + r;
        *(u16*)(lP + ml * 128 + (nl2 ^ ((ml & 7) << 4))) = f2b(pval);
      }
    }
    // mid barrier: lP visible, but do NOT drain vmcnt (prefetch stays in flight)
    asm volatile("s_waitcnt lgkmcnt(0)" ::: "memory");
    __builtin_amdgcn_sched_barrier(0);
    __builtin_amdgcn_s_barrier();
    // PV phase: wave's 16 d-rows x 128 m
    for (int ks2 = 0; ks2 < 2; ks2++) {
      int kb2 = ks2 * 64 + (lane >> 4) * 16;
      int vrow = wid * 16 + (lane & 15);
      bf16x8 av = *(const bf16x8*)(lV[cur] + vrow * 128 + (kb2 ^ ((vrow & 7) << 4)));
      for (int fm = 0; fm < 8; fm++) {
        int row = fm * 16 + (lane & 15);
        bf16x8 bp = *(const bf16x8*)(lP + row * 128 + (kb2 ^ ((row & 7) << 4)));
        oacc[fm] = mfma16(av, bp, oacc[fm]);
      }
    }
  }
  // epilogue: store o + fused gate partial (sum_d gw[c]*o[c][m])
  float gwl[4];
  for (int r = 0; r < 4; r++)
    gwl[r] = gw[h * DK_ + wid * 16 + (lane >> 4) * 4 + r];
  __syncthreads();
  for (int fm = 0; fm < 8; fm++) {
    int m = fm * 16 + (lane & 15);
    int d = wid * 16 + (lane >> 4) * 4;
    float part = 0.f;
    for (int r = 0; r < 4; r++) {
      float val = oacc[fm][r];
      ob[(size_t)(d + r) * N_ + m] = val;
      part += gwl[r] * val;
    }
    atomicAdd(&gacc[m], part);
  }
  __syncthreads();
  if (t < 128) atomicAdd(&g[(size_t)b * N_ + mb + t], gacc[t]);
}

// ---------------- gate finish ----------------
__global__ __launch_bounds__(256) void k_zero_g(float* __restrict__ g) {
  g[blockIdx.x * 256 + threadIdx.x] = 0.f;
}

__global__ __launch_bounds__(256) void k_gate_apply(const float* __restrict__ g,
                                                    const float* __restrict__ gb,
                                                    float* __restrict__ out) {
  size_t i = ((size_t)blockIdx.x * 256 + threadIdx.x) * 4;
  int b = (int)(i / ((size_t)C_ * N_));
  int n = (int)(i & (N_ - 1));
  float4 gv = *(const float4*)(g + (size_t)b * N_ + n);
  float bias = gb[0];
  float4 v = *(float4*)(out + i);
  v.x *= 1.f + 1.f / (1.f + __expf(-(gv.x + bias)));
  v.y *= 1.f + 1.f / (1.f + __expf(-(gv.y + bias)));
  v.z *= 1.f + 1.f / (1.f + __expf(-(gv.z + bias)));
  v.w *= 1.f + 1.f / (1.f + __expf(-(gv.w + bias)));
  *(float4*)(out + i) = v;
}

extern "C" void kernel_launch(void* const* d_in, const int* in_sizes, int n_in,
                              void* d_out, int out_size, void* d_ws, size_t ws_size,
                              hipStream_t stream) {
  const float* x    = (const float*)d_in[0];
  const float* wq   = (const float*)d_in[1];
  const float* bq   = (const float*)d_in[2];
  const float* wk   = (const float*)d_in[3];
  const float* bk   = (const float*)d_in[4];
  const float* wv   = (const float*)d_in[5];
  const float* bv   = (const float*)d_in[6];
  const float* fc1w = (const float*)d_in[7];
  const float* fc1b = (const float*)d_in[8];
  const float* fc2w = (const float*)d_in[9];
  const float* fc2b = (const float*)d_in[10];
  const float* gw   = (const float*)d_in[11];
  const float* gb   = (const float*)d_in[12];
  float* out = (float*)d_out;
  char* ws = (char*)d_ws;

  float* p   = (float*)(ws + OFF_P);
  float* ssc = (float*)(ws + OFF_SS);
  u16* wb  = (u16*)(ws + OFF_WB);
  u16* xt  = (u16*)(ws + OFF_XT);
  u16* qt  = (u16*)(ws + OFF_QT);
  u16* kt  = (u16*)(ws + OFF_KT);
  u16* v   = (u16*)(ws + OFF_V);
  float* den = (float*)(ws + OFF_DEN);
  float* g   = (float*)(ws + OFF_G);

  k_pool<<<B_ * C_, 64, 0, stream>>>(x, p);
  k_castw<<<768, 256, 0, stream>>>(wq, wk, wv, wb);
  k_se<<<B_, 256, 0, stream>>>(p, fc1w, fc1b, fc2w, fc2b, ssc);
  k_zero_g<<<B_ * N_ / 256, 256, 0, stream>>>(g);
  k_xt<<<dim3(16, 8, B_), 256, 0, stream>>>(x, ssc, xt);
  k_qkv<<<dim3(32, B_ * 3), 256, 0, stream>>>(xt, wb, bq, bk, bv, qt, kt, v);
  k_passA<<<dim3(32, 8), 512, 0, stream>>>(qt, kt, den);
  k_passB<<<dim3(32, 8), 512, 0, stream>>>(qt, kt, v, den, gw, out, g);
  k_gate_apply<<<B_ * C_ * N_ / 1024, 256, 0, stream>>>(g, gb, out);
}